// Round 14
// baseline (881.022 us; speedup 1.0000x reference)
//
#include <hip/hip_runtime.h>
#include <math.h>

#define HD 2048
#define NACT 16
#define NSTEP 24
#define WL (4*HD*HD)        // per-layer per-matrix elems (16,777,216)
#define NIH (2*WL)          // elems in w_ih (both layers) = 33,554,432

#define NWG 256             // proven co-resident (1 block/CU)
#define NTHR 512            // 8 waves: 1 wave per hidden unit, full-K
#define NWG_FB 256
#define NTHR_FB 512

typedef float  nf4 __attribute__((ext_vector_type(4)));   // native vec for NT builtins
typedef const void __attribute__((address_space(1))) gas_void;
typedef void __attribute__((address_space(3))) las_void;

// ---------------- agent-scope (cross-XCD coherent) access helpers ----------------
__device__ __forceinline__ float ld_agent(const float* p) {
  return __hip_atomic_load(p, __ATOMIC_RELAXED, __HIP_MEMORY_SCOPE_AGENT);
}
__device__ __forceinline__ float2 ld_agent2(const float* p) {   // 8B coherent load
  unsigned long long v = __hip_atomic_load((const unsigned long long*)p,
                                           __ATOMIC_RELAXED, __HIP_MEMORY_SCOPE_AGENT);
  float2 r;
  r.x = __uint_as_float((unsigned)v);
  r.y = __uint_as_float((unsigned)(v >> 32));
  return r;
}
__device__ __forceinline__ void st_agent(float* p, float v) {
  __hip_atomic_store(p, v, __ATOMIC_RELAXED, __HIP_MEMORY_SCOPE_AGENT);
}

// async global->LDS copy, 16B per lane. LDS dest = uniform base + lane*16;
// global src = per-lane address.
__device__ __forceinline__ void gl16(const unsigned* g, unsigned* l) {
  __builtin_amdgcn_global_load_lds((gas_void*)g, (las_void*)l, 16, 0, 0);
}

#define WAITVM8 { asm volatile("s_waitcnt vmcnt(8)" ::: "memory"); __builtin_amdgcn_sched_barrier(0); }
#define WAITVM0 { asm volatile("s_waitcnt vmcnt(0)" ::: "memory"); __builtin_amdgcn_sched_barrier(0); }
#define SB      { __builtin_amdgcn_sched_barrier(0); }

// ---------------- threefry2x32-20 (JAX partitionable semantics) ----------------
__device__ __forceinline__ unsigned rotl32(unsigned v, int r) { return (v << r) | (v >> (32 - r)); }

__device__ __forceinline__ void threefry(unsigned k0, unsigned k1, unsigned x0, unsigned x1,
                                         unsigned& o0, unsigned& o1) {
  unsigned ks2 = k0 ^ k1 ^ 0x1BD11BDAu;
#define TFR(r) { x0 += x1; x1 = rotl32(x1, r); x1 ^= x0; }
  x0 += k0; x1 += k1;
  TFR(13) TFR(15) TFR(26) TFR(6)
  x0 += k1;  x1 += ks2 + 1u;
  TFR(17) TFR(29) TFR(16) TFR(24)
  x0 += ks2; x1 += k0 + 2u;
  TFR(13) TFR(15) TFR(26) TFR(6)
  x0 += k0;  x1 += k1 + 3u;
  TFR(17) TFR(29) TFR(16) TFR(24)
  x0 += k1;  x1 += ks2 + 4u;
  TFR(13) TFR(15) TFR(26) TFR(6)
  x0 += ks2; x1 += k0 + 5u;
#undef TFR
  o0 = x0; o1 = x1;
}

__device__ __forceinline__ float sigmoidf(float x) { return 1.0f / (1.0f + expf(-x)); }

// bf16 helpers
__device__ __forceinline__ unsigned f2bf(float f) {          // round-to-nearest-even
  unsigned u = __float_as_uint(f);
  return (u + 0x7fffu + ((u >> 16) & 1u)) >> 16;
}
#define BF_LO(u) __uint_as_float((u) << 16)
#define BF_HI(u) __uint_as_float((u) & 0xffff0000u)

// ---------------- two-level release barrier, fence-free ----------------
__device__ void grid_bar(unsigned* flags, unsigned* release, unsigned ep) {
  __syncthreads();
  if (threadIdx.x == 0) {
    __hip_atomic_store(&flags[blockIdx.x], ep, __ATOMIC_RELAXED, __HIP_MEMORY_SCOPE_AGENT);
  }
  if (blockIdx.x == 0) {
    if (threadIdx.x < 64) {
      const unsigned* my = flags + threadIdx.x * 4;
      long guard = 0;
      for (;;) {
        unsigned f0 = __hip_atomic_load(my + 0, __ATOMIC_RELAXED, __HIP_MEMORY_SCOPE_AGENT);
        unsigned f1 = __hip_atomic_load(my + 1, __ATOMIC_RELAXED, __HIP_MEMORY_SCOPE_AGENT);
        unsigned f2 = __hip_atomic_load(my + 2, __ATOMIC_RELAXED, __HIP_MEMORY_SCOPE_AGENT);
        unsigned f3 = __hip_atomic_load(my + 3, __ATOMIC_RELAXED, __HIP_MEMORY_SCOPE_AGENT);
        bool ok = (f0 >= ep) && (f1 >= ep) && (f2 >= ep) && (f3 >= ep);
        if (__all(ok)) break;
        if (++guard > 1000000L) break;
        __builtin_amdgcn_s_sleep(2);
      }
      if (threadIdx.x == 0) {
        __hip_atomic_store(release, ep, __ATOMIC_RELAXED, __HIP_MEMORY_SCOPE_AGENT);
      }
    }
  } else {
    if (threadIdx.x == 0) {
      long guard = 0;
      while (__hip_atomic_load(release, __ATOMIC_RELAXED, __HIP_MEMORY_SCOPE_AGENT) < ep &&
             guard < 1000000L) {
        __builtin_amdgcn_s_sleep(4);
        ++guard;
      }
    }
  }
  __syncthreads();
}

// ---------------- logits + categorical sample (redundant per wg, 8 waves) ----------------
__device__ int sample_step(const float* __restrict__ h1g, const float* __restrict__ soft_w,
                           int t, float* lp_out, float* ent_out) {
  __shared__ float s_part[8][NACT];
  __shared__ float s_res[3];
  const int wave = threadIdx.x >> 6;
  const int lane = threadIdx.x & 63;

  float lg[NACT];
#pragma unroll
  for (int a = 0; a < NACT; ++a) lg[a] = 0.0f;
#pragma unroll
  for (int m = 0; m < 2; ++m) {
    int p = wave * 128 + m * 64 + lane;      // pair index; covers elems 2p, 2p+1
    float2 hv = ld_agent2(h1g + p * 2);      // one 8B coherent load
    const float* sw0 = soft_w + (size_t)(p * 2) * NACT;
    const float* sw1 = sw0 + NACT;
#pragma unroll
    for (int h = 0; h < 2; ++h) {
      const float* sw = h ? sw1 : sw0;
      float hvv = h ? hv.y : hv.x;
      float4 r0 = *(const float4*)(sw);
      float4 r1 = *(const float4*)(sw + 4);
      float4 r2 = *(const float4*)(sw + 8);
      float4 r3 = *(const float4*)(sw + 12);
      lg[0]  += hvv * r0.x; lg[1]  += hvv * r0.y; lg[2]  += hvv * r0.z; lg[3]  += hvv * r0.w;
      lg[4]  += hvv * r1.x; lg[5]  += hvv * r1.y; lg[6]  += hvv * r1.z; lg[7]  += hvv * r1.w;
      lg[8]  += hvv * r2.x; lg[9]  += hvv * r2.y; lg[10] += hvv * r2.z; lg[11] += hvv * r2.w;
      lg[12] += hvv * r3.x; lg[13] += hvv * r3.y; lg[14] += hvv * r3.z; lg[15] += hvv * r3.w;
    }
  }
#pragma unroll
  for (int off = 32; off > 0; off >>= 1) {
#pragma unroll
    for (int a = 0; a < NACT; ++a) lg[a] += __shfl_xor(lg[a], off, 64);
  }
  if (lane == 0) {
#pragma unroll
    for (int a = 0; a < NACT; ++a) s_part[wave][a] = lg[a];
  }
  __syncthreads();

  if (wave == 0 && lane < NACT) {
    float logit = 0.0f;
#pragma unroll
    for (int w = 0; w < 8; ++w) logit += s_part[w][lane];

    unsigned kt0, kt1, b0, b1;
    threefry(0u, 42u, 0u, (unsigned)t, kt0, kt1);
    threefry(kt0, kt1, 0u, (unsigned)lane, b0, b1);
    unsigned bits = b0 ^ b1;

    const float tiny = 1.17549435e-38f;
    float u = __uint_as_float((bits >> 9) | 0x3f800000u) - 1.0f;  // [0,1)
    u = fmaxf(tiny, u + tiny);
    float gmb = -logf(-logf(u));
    float z = logit + gmb;

    int idx = lane; float zz = z;
#pragma unroll
    for (int off = 8; off > 0; off >>= 1) {
      float oz = __shfl_xor(zz, off, NACT);
      int   oi = __shfl_xor(idx, off, NACT);
      if (oz > zz || (oz == zz && oi < idx)) { zz = oz; idx = oi; }
    }
    float mx = logit;
#pragma unroll
    for (int off = 8; off > 0; off >>= 1) mx = fmaxf(mx, __shfl_xor(mx, off, NACT));
    float sh = logit - mx;
    float se = expf(sh);
#pragma unroll
    for (int off = 8; off > 0; off >>= 1) se += __shfl_xor(se, off, NACT);
    float lp = sh - logf(se);
    float term = expf(lp) * lp;
#pragma unroll
    for (int off = 8; off > 0; off >>= 1) term += __shfl_xor(term, off, NACT);
    float lp_sel = __shfl(lp, idx, NACT);
    if (lane == 0) { s_res[0] = (float)idx; s_res[1] = lp_sel; s_res[2] = -term; }
  }
  __syncthreads();
  int act = (int)s_res[0];
  *lp_out = s_res[1];
  *ent_out = s_res[2];
  return act;
}

// =======================================================================
//                     FAST PATH: bf16 weights in d_ws
// =======================================================================

// f32 -> bf16 conversion, 8 elems/thread. NT loads for the single-use f32 stream.
__global__ void __launch_bounds__(256) conv_bf16(const float* __restrict__ src,
                                                 unsigned* __restrict__ dst) {
  size_t i = ((size_t)blockIdx.x * blockDim.x + threadIdx.x) * 8;
  const nf4* s4 = (const nf4*)(src + i);
  nf4 a = __builtin_nontemporal_load(s4);
  nf4 b = __builtin_nontemporal_load(s4 + 1);
  uint4 o;
  o.x = (f2bf(a.y) << 16) | f2bf(a.x);
  o.y = (f2bf(a.w) << 16) | f2bf(a.z);
  o.z = (f2bf(b.y) << 16) | f2bf(b.x);
  o.w = (f2bf(b.w) << 16) | f2bf(b.z);
  *(uint4*)(dst + i / 2) = o;
}

// prefetch one 4KB weight row (1024 uints) into LDS via 4 global_load_lds
__device__ __forceinline__ void row_prefetch(const unsigned* __restrict__ wrow,
                                             unsigned* ldst, int lane) {
#pragma unroll
  for (int cc = 0; cc < 4; ++cc)
    gl16(wrow + cc * 256 + lane * 4, ldst + cc * 256);
}

// dot of one gate from an LDS buffer (wi at +0, wh at +1024); byte-identical
// math to R11/R13 (uint2 weights, dense float4 x/h).
__device__ __forceinline__ float gate_dot(const unsigned* wbuf,
                                          const float4* xv, const float4* hv, int lane) {
  const unsigned* wi_l = wbuf;
  const unsigned* wh_l = wbuf + 1024;
  float si = 0.0f, sh2 = 0.0f;
#pragma unroll
  for (int k = 0; k < 8; ++k) {
    uint2 qa = *(const uint2*)(wi_l + k * 128 + lane * 2);
    uint2 qb = *(const uint2*)(wh_l + k * 128 + lane * 2);
    si  += BF_LO(qa.x) * xv[k].x + BF_HI(qa.x) * xv[k].y;
    si  += BF_LO(qa.y) * xv[k].z + BF_HI(qa.y) * xv[k].w;
    sh2 += BF_LO(qb.x) * hv[k].x + BF_HI(qb.x) * hv[k].y;
    sh2 += BF_LO(qb.y) * hv[k].z + BF_HI(qb.y) * hv[k].w;
  }
  return si + sh2;
}

#define GS (((size_t)HD * HD) >> 1)   // uints per gate block (2,097,152)

// one LSTM layer phase with deep LDS weight pipeline.
// Precondition: gates 0,1 of (wiL,whL) already in s_wv buf0/buf1 (prefetched
// before the preceding barrier). Postcondition: gates 0,1 of (nwiL,nwhL)
// issued into buf0/buf1 (stream during the following barrier).
__device__ void layer_phase(const unsigned* __restrict__ wiL, const unsigned* __restrict__ whL,
                            const unsigned* __restrict__ nwiL, const unsigned* __restrict__ nwhL,
                            const float* __restrict__ bihL, const float* __restrict__ bhhL,
                            const float* __restrict__ x, bool x_is_shared_state,
                            const float* __restrict__ hin,
                            float* __restrict__ hout, float* __restrict__ c,
                            float* s_x, float* s_h, unsigned* s_wv,
                            int j, int lane) {
  const int tid = threadIdx.x;
  // ---- cooperative stage of x (2048) and h (2048) into LDS ----
  if (x_is_shared_state) {
    float2 a = ld_agent2(x + tid * 2);
    float2 b = ld_agent2(x + 1024 + tid * 2);
    *(float2*)(s_x + tid * 2) = a;
    *(float2*)(s_x + 1024 + tid * 2) = b;
  } else {
    *(float4*)(s_x + tid * 4) = *(const float4*)(x + tid * 4);
  }
  {
    float2 ha = ld_agent2(hin + tid * 2);
    float2 hb = ld_agent2(hin + 1024 + tid * 2);
    *(float2*)(s_h + tid * 2) = ha;
    *(float2*)(s_h + 1024 + tid * 2) = hb;
  }
  __syncthreads();   // also drains vmcnt -> gates 0,1 guaranteed resident

  // register-stage x/h: chunk k covers elems [k*256 + lane*4, +4)
  float4 xv[8], hv[8];
#pragma unroll
  for (int k = 0; k < 8; ++k) {
    int e = k * 256 + lane * 4;
    xv[k] = *(const float4*)(s_x + e);
    hv[k] = *(const float4*)(s_h + e);
  }

  const size_t jrow = (size_t)j * 1024;   // uints to row j within a gate block
  float acc[4];

  acc[0] = gate_dot(s_wv, xv, hv, lane);             // g0 from buf0
  SB;
  row_prefetch(wiL + 2 * GS + jrow, s_wv, lane);     // g2 -> buf0 (8 loads)
  row_prefetch(whL + 2 * GS + jrow, s_wv + 1024, lane);
  acc[1] = gate_dot(s_wv + 2048, xv, hv, lane);      // g1 from buf1
  SB;
  row_prefetch(wiL + 3 * GS + jrow, s_wv + 2048, lane);   // g3 -> buf1
  row_prefetch(whL + 3 * GS + jrow, s_wv + 3072, lane);
  WAITVM8;                                           // g2 landed
  acc[2] = gate_dot(s_wv, xv, hv, lane);
  WAITVM0;                                           // g3 landed
  acc[3] = gate_dot(s_wv + 2048, xv, hv, lane);
  SB;
  // next phase's gates 0,1 -> stream during the upcoming barrier
  row_prefetch(nwiL + jrow, s_wv, lane);
  row_prefetch(nwhL + jrow, s_wv + 1024, lane);
  row_prefetch(nwiL + GS + jrow, s_wv + 2048, lane);
  row_prefetch(nwhL + GS + jrow, s_wv + 3072, lane);

#pragma unroll
  for (int off = 32; off > 0; off >>= 1) {
#pragma unroll
    for (int g = 0; g < 4; ++g) acc[g] += __shfl_xor(acc[g], off, 64);
  }
  if (lane == 0) {
    float gi = acc[0] + bihL[j]          + bhhL[j];
    float gf = acc[1] + bihL[HD + j]     + bhhL[HD + j];
    float gg = acc[2] + bihL[2 * HD + j] + bhhL[2 * HD + j];
    float go = acc[3] + bihL[3 * HD + j] + bhhL[3 * HD + j];
    float cn = sigmoidf(gf) * c[j] + sigmoidf(gi) * tanhf(gg);
    c[j] = cn;                                     // wg-private (same CU)
    st_agent(&hout[j], sigmoidf(go) * tanhf(cn));  // cross-wg coherent
  }
}

__global__ void __launch_bounds__(NTHR) ctrl2_kernel(
    const float* __restrict__ g_emb, const float* __restrict__ w_emb,
    const float* __restrict__ soft_w,
    const unsigned* __restrict__ wb_ih, const unsigned* __restrict__ wb_hh,
    const float* __restrict__ b_ih, const float* __restrict__ b_hh,
    float* __restrict__ out, float* __restrict__ state,
    unsigned* __restrict__ flags, unsigned* __restrict__ release) {
  __shared__ float s_x[HD];
  __shared__ float s_h[HD];
  __shared__ unsigned s_w[8 * 4096];     // 8 waves x 2 bufs x 2048 uints = 128 KB
  float* h0 = state;            // [2][HD] ping-pong
  float* h1 = state + 2 * HD;   // [2][HD] ping-pong
  float* c0 = state + 4 * HD;
  float* c1 = state + 5 * HD;

  const int tid  = threadIdx.x;
  const int wave = tid >> 6;
  const int lane = tid & 63;
  const int j = (int)blockIdx.x * 8 + wave;
  unsigned* s_wv = s_w + wave * 4096;    // this wave's [2][2048] region

  if (tid < 8) {
    int jj = (int)blockIdx.x * 8 + tid;
    st_agent(&h0[jj], 0.0f); st_agent(&h1[jj], 0.0f);
    c0[jj] = 0.0f; c1[jj] = 0.0f;
  }

  const unsigned* wi0 = wb_ih;             const unsigned* wh0 = wb_hh;
  const unsigned* wi1 = wb_ih + WL / 2;    const unsigned* wh1 = wb_hh + WL / 2;
  const size_t jrow = (size_t)j * 1024;

  // prologue: L0 gates 0,1 stream during the init barrier
  row_prefetch(wi0 + jrow, s_wv, lane);
  row_prefetch(wh0 + jrow, s_wv + 1024, lane);
  row_prefetch(wi0 + GS + jrow, s_wv + 2048, lane);
  row_prefetch(wh0 + GS + jrow, s_wv + 3072, lane);

  unsigned ep = 1;
  grid_bar(flags, release, ep++);

  const float* x = g_emb;
  for (int t = 0; t < NSTEP; ++t) {
    int q = t & 1;
    layer_phase(wi0, wh0, wi1, wh1, b_ih, b_hh, x, /*x shared=*/false,
                h0 + q * HD, h0 + (1 - q) * HD, c0, s_x, s_h, s_wv, j, lane);
    grid_bar(flags, release, ep++);
    layer_phase(wi1, wh1, wi0, wh0, b_ih + 4 * HD, b_hh + 4 * HD,
                h0 + (1 - q) * HD, /*x shared=*/true,
                h1 + q * HD, h1 + (1 - q) * HD, c1, s_x, s_h, s_wv, j, lane);
    grid_bar(flags, release, ep++);
    float lp, en;
    int act = sample_step(h1 + (1 - q) * HD, soft_w, t, &lp, &en);
    if (blockIdx.x == 0 && tid == 0) {
      out[t] = (float)act;
      out[NSTEP + t] = lp;
      out[2 * NSTEP + t] = en;
    }
    x = w_emb + (size_t)act * HD;
  }
}

// =======================================================================
//          FALLBACK PATH: f32 weights direct (round-5-proven, 256x512)
// =======================================================================

__device__ void grid_bar_ctr(unsigned long long* ctr, unsigned long long target) {
  __syncthreads();
  if (threadIdx.x == 0) {
    __builtin_amdgcn_fence(__ATOMIC_SEQ_CST, "agent");
    __hip_atomic_fetch_add(ctr, 1ull, __ATOMIC_RELAXED, __HIP_MEMORY_SCOPE_AGENT);
    long guard = 0;
    while (__hip_atomic_load(ctr, __ATOMIC_RELAXED, __HIP_MEMORY_SCOPE_AGENT) < target &&
           guard < 20000000L) {
      __builtin_amdgcn_s_sleep(2);
      ++guard;
    }
    __builtin_amdgcn_fence(__ATOMIC_SEQ_CST, "agent");
  }
  __syncthreads();
}

__device__ int sample_step8(const float* __restrict__ h1g, const float* __restrict__ soft_w,
                            int t, float* lp_out, float* ent_out) {
  __shared__ float s_part[8][NACT];
  __shared__ float s_res[3];
  const int wave = threadIdx.x >> 6;
  const int lane = threadIdx.x & 63;

  float lg[NACT];
#pragma unroll
  for (int a = 0; a < NACT; ++a) lg[a] = 0.0f;
#pragma unroll
  for (int m = 0; m < 4; ++m) {
    int e = wave * 256 + m * 64 + lane;
    float hv = h1g[e];
    const float* sw = soft_w + (size_t)e * NACT;
    float4 r0 = *(const float4*)(sw);
    float4 r1 = *(const float4*)(sw + 4);
    float4 r2 = *(const float4*)(sw + 8);
    float4 r3 = *(const float4*)(sw + 12);
    lg[0]  += hv * r0.x; lg[1]  += hv * r0.y; lg[2]  += hv * r0.z; lg[3]  += hv * r0.w;
    lg[4]  += hv * r1.x; lg[5]  += hv * r1.y; lg[6]  += hv * r1.z; lg[7]  += hv * r1.w;
    lg[8]  += hv * r2.x; lg[9]  += hv * r2.y; lg[10] += hv * r2.z; lg[11] += hv * r2.w;
    lg[12] += hv * r3.x; lg[13] += hv * r3.y; lg[14] += hv * r3.z; lg[15] += hv * r3.w;
  }
#pragma unroll
  for (int off = 32; off > 0; off >>= 1) {
#pragma unroll
    for (int a = 0; a < NACT; ++a) lg[a] += __shfl_xor(lg[a], off, 64);
  }
  if (lane == 0) {
#pragma unroll
    for (int a = 0; a < NACT; ++a) s_part[wave][a] = lg[a];
  }
  __syncthreads();

  if (wave == 0 && lane < NACT) {
    float logit = 0.0f;
#pragma unroll
    for (int w = 0; w < 8; ++w) logit += s_part[w][lane];
    unsigned kt0, kt1, b0, b1;
    threefry(0u, 42u, 0u, (unsigned)t, kt0, kt1);
    threefry(kt0, kt1, 0u, (unsigned)lane, b0, b1);
    unsigned bits = b0 ^ b1;
    const float tiny = 1.17549435e-38f;
    float u = __uint_as_float((bits >> 9) | 0x3f800000u) - 1.0f;
    u = fmaxf(tiny, u + tiny);
    float gmb = -logf(-logf(u));
    float z = logit + gmb;
    int idx = lane; float zz = z;
#pragma unroll
    for (int off = 8; off > 0; off >>= 1) {
      float oz = __shfl_xor(zz, off, NACT);
      int   oi = __shfl_xor(idx, off, NACT);
      if (oz > zz || (oz == zz && oi < idx)) { zz = oz; idx = oi; }
    }
    float mx = logit;
#pragma unroll
    for (int off = 8; off > 0; off >>= 1) mx = fmaxf(mx, __shfl_xor(mx, off, NACT));
    float sh = logit - mx;
    float se = expf(sh);
#pragma unroll
    for (int off = 8; off > 0; off >>= 1) se += __shfl_xor(se, off, NACT);
    float lp = sh - logf(se);
    float term = expf(lp) * lp;
#pragma unroll
    for (int off = 8; off > 0; off >>= 1) term += __shfl_xor(term, off, NACT);
    float lp_sel = __shfl(lp, idx, NACT);
    if (lane == 0) { s_res[0] = (float)idx; s_res[1] = lp_sel; s_res[2] = -term; }
  }
  __syncthreads();
  int act = (int)s_res[0];
  *lp_out = s_res[1];
  *ent_out = s_res[2];
  return act;
}

__device__ void lstm_layer(const float* __restrict__ Wih, const float* __restrict__ Whh,
                           const float* __restrict__ bih, const float* __restrict__ bhh,
                           const float* __restrict__ x, const float* __restrict__ hin,
                           float* __restrict__ hout, float* __restrict__ c) {
  const int wave = threadIdx.x >> 6;
  const int lane = threadIdx.x & 63;
  const int j = (int)blockIdx.x * 8 + wave;

  float4 xv[8], hv[8];
#pragma unroll
  for (int k = 0; k < 8; ++k) {
    int e = k * 256 + lane * 4;
    xv[k] = *(const float4*)(x + e);
    hv[k] = *(const float4*)(hin + e);
  }
  float acc[4];
#pragma unroll
  for (int g = 0; g < 4; ++g) {
    const float* wi = Wih + (size_t)(g * HD + j) * HD;
    const float* wh = Whh + (size_t)(g * HD + j) * HD;
    float s = 0.0f;
#pragma unroll
    for (int k = 0; k < 8; ++k) {
      int e = k * 256 + lane * 4;
      float4 a4 = *(const float4*)(wi + e);
      float4 b4 = *(const float4*)(wh + e);
      s += a4.x * xv[k].x; s += a4.y * xv[k].y; s += a4.z * xv[k].z; s += a4.w * xv[k].w;
      s += b4.x * hv[k].x; s += b4.y * hv[k].y; s += b4.z * hv[k].z; s += b4.w * hv[k].w;
    }
    acc[g] = s;
  }
#pragma unroll
  for (int off = 32; off > 0; off >>= 1) {
#pragma unroll
    for (int g = 0; g < 4; ++g) acc[g] += __shfl_xor(acc[g], off, 64);
  }
  if (lane == 0) {
    float gi = acc[0] + bih[j]          + bhh[j];
    float gf = acc[1] + bih[HD + j]     + bhh[HD + j];
    float gg = acc[2] + bih[2 * HD + j] + bhh[2 * HD + j];
    float go = acc[3] + bih[3 * HD + j] + bhh[3 * HD + j];
    float cn = sigmoidf(gf) * c[j] + sigmoidf(gi) * tanhf(gg);
    c[j] = cn;
    hout[j] = sigmoidf(go) * tanhf(cn);
  }
}

__global__ void __launch_bounds__(NTHR_FB) ctrl_kernel(
    const float* __restrict__ g_emb, const float* __restrict__ w_emb,
    const float* __restrict__ soft_w, const float* __restrict__ w_ih,
    const float* __restrict__ w_hh, const float* __restrict__ b_ih,
    const float* __restrict__ b_hh, float* __restrict__ out, float* __restrict__ ws) {
  float* h0 = ws;
  float* h1 = ws + 2 * HD;
  float* c0 = ws + 4 * HD;
  float* c1 = ws + 5 * HD;
  unsigned long long* bar = (unsigned long long*)(ws + 6 * HD);

  if (threadIdx.x < 8) {
    int j = (int)blockIdx.x * 8 + (int)threadIdx.x;
    h0[j] = 0.0f; h1[j] = 0.0f; c0[j] = 0.0f; c1[j] = 0.0f;
  }
  unsigned long long ep = 1;
  grid_bar_ctr(bar, (ep++) * NWG_FB);

  const float* x = g_emb;
  for (int t = 0; t < NSTEP; ++t) {
    int q = t & 1;
    lstm_layer(w_ih, w_hh, b_ih, b_hh, x, h0 + q * HD, h0 + (1 - q) * HD, c0);
    grid_bar_ctr(bar, (ep++) * NWG_FB);
    lstm_layer(w_ih + WL, w_hh + WL, b_ih + 4 * HD, b_hh + 4 * HD,
               h0 + (1 - q) * HD, h1 + q * HD, h1 + (1 - q) * HD, c1);
    grid_bar_ctr(bar, (ep++) * NWG_FB);
    float lp, en;
    int act = sample_step8(h1 + (1 - q) * HD, soft_w, t, &lp, &en);
    if (blockIdx.x == 0 && threadIdx.x == 0) {
      out[t] = (float)act;
      out[NSTEP + t] = lp;
      out[2 * NSTEP + t] = en;
    }
    x = w_emb + (size_t)act * HD;
  }
}

__global__ void init_sync(unsigned* flags) {            // zero flags + release area
  flags[threadIdx.x] = 0u;
}
__global__ void init_bar(unsigned long long* bar) { *bar = 0ull; }

extern "C" void kernel_launch(void* const* d_in, const int* in_sizes, int n_in,
                              void* d_out, int out_size, void* d_ws, size_t ws_size,
                              hipStream_t stream) {
  const float* g_emb  = (const float*)d_in[0];
  const float* w_emb  = (const float*)d_in[1];
  const float* soft_w = (const float*)d_in[2];
  const float* w_ih   = (const float*)d_in[3];
  const float* w_hh   = (const float*)d_in[4];
  const float* b_ih   = (const float*)d_in[5];
  const float* b_hh   = (const float*)d_in[6];

  const size_t wbytes = (size_t)NIH * 2 * sizeof(unsigned short);  // 134,217,728
  const size_t need = wbytes + (size_t)6 * HD * sizeof(float) + 512 * sizeof(unsigned) + 64;

  if (ws_size >= need) {
    unsigned* wb_ih = (unsigned*)d_ws;               // NIH bf16 = NIH/2 uints
    unsigned* wb_hh = wb_ih + NIH / 2;
    float* state = (float*)((char*)d_ws + wbytes);
    unsigned* flags = (unsigned*)(state + 6 * HD);   // 256 arrival flags
    unsigned* release = flags + 320;                 // own cache line, within 512 zeroed

    hipLaunchKernelGGL(init_sync, dim3(1), dim3(512), 0, stream, flags);
    hipLaunchKernelGGL(conv_bf16, dim3(NIH / (256 * 8)), dim3(256), 0, stream, w_ih, wb_ih);
    hipLaunchKernelGGL(conv_bf16, dim3(NIH / (256 * 8)), dim3(256), 0, stream, w_hh, wb_hh);
    hipLaunchKernelGGL(ctrl2_kernel, dim3(NWG), dim3(NTHR), 0, stream,
                       g_emb, w_emb, soft_w, wb_ih, wb_hh, b_ih, b_hh,
                       (float*)d_out, state, flags, release);
  } else {
    float* ws = (float*)d_ws;
    unsigned long long* bar = (unsigned long long*)(ws + 6 * HD);
    hipLaunchKernelGGL(init_bar, dim3(1), dim3(1), 0, stream, bar);
    hipLaunchKernelGGL(ctrl_kernel, dim3(NWG_FB), dim3(NTHR_FB), 0, stream,
                       g_emb, w_emb, soft_w, w_ih, w_hh, b_ih, b_hh,
                       (float*)d_out, ws);
  }
}

// Round 15
// 832.448 us; speedup vs baseline: 1.0583x; 1.0583x over previous
//
#include <hip/hip_runtime.h>
#include <math.h>

#define HD 2048
#define NACT 16
#define NSTEP 24
#define WL (4*HD*HD)        // per-layer per-matrix elems (16,777,216)
#define NIH (2*WL)          // elems in w_ih (both layers) = 33,554,432

#define NWG 256             // proven co-resident (1 block/CU)
#define NTHR 512            // 8 waves: 1 wave per hidden unit, full-K (R13 core)
#define NWG_FB 256
#define NTHR_FB 512

typedef float  nf4 __attribute__((ext_vector_type(4)));   // native vec for NT builtins
typedef unsigned long long u64;

// ---------------- agent-scope (cross-XCD coherent) access helpers ----------------
__device__ __forceinline__ u64 ld64_agent(const u64* p) {
  return __hip_atomic_load(p, __ATOMIC_RELAXED, __HIP_MEMORY_SCOPE_AGENT);
}
__device__ __forceinline__ void st64_agent(u64* p, u64 v) {
  __hip_atomic_store(p, v, __ATOMIC_RELAXED, __HIP_MEMORY_SCOPE_AGENT);
}

// poll one tagged h element until its epoch matches; first try is fast-path.
__device__ __forceinline__ float poll_tag(const u64* a, unsigned tag) {
  u64 v = ld64_agent(a);
  if ((unsigned)(v >> 32) != tag) {
    long g = 0;
    do {
      __builtin_amdgcn_s_sleep(1);
      v = ld64_agent(a);
    } while ((unsigned)(v >> 32) != tag && ++g < 1000000L);
  }
  return __uint_as_float((unsigned)v);
}

// ---------------- threefry2x32-20 (JAX partitionable semantics) ----------------
__device__ __forceinline__ unsigned rotl32(unsigned v, int r) { return (v << r) | (v >> (32 - r)); }

__device__ __forceinline__ void threefry(unsigned k0, unsigned k1, unsigned x0, unsigned x1,
                                         unsigned& o0, unsigned& o1) {
  unsigned ks2 = k0 ^ k1 ^ 0x1BD11BDAu;
#define TFR(r) { x0 += x1; x1 = rotl32(x1, r); x1 ^= x0; }
  x0 += k0; x1 += k1;
  TFR(13) TFR(15) TFR(26) TFR(6)
  x0 += k1;  x1 += ks2 + 1u;
  TFR(17) TFR(29) TFR(16) TFR(24)
  x0 += ks2; x1 += k0 + 2u;
  TFR(13) TFR(15) TFR(26) TFR(6)
  x0 += k0;  x1 += k1 + 3u;
  TFR(17) TFR(29) TFR(16) TFR(24)
  x0 += k1;  x1 += ks2 + 4u;
  TFR(13) TFR(15) TFR(26) TFR(6)
  x0 += ks2; x1 += k0 + 5u;
#undef TFR
  o0 = x0; o1 = x1;
}

__device__ __forceinline__ float sigmoidf(float x) { return 1.0f / (1.0f + expf(-x)); }

// bf16 helpers
__device__ __forceinline__ unsigned f2bf(float f) {          // round-to-nearest-even
  unsigned u = __float_as_uint(f);
  return (u + 0x7fffu + ((u >> 16) & 1u)) >> 16;
}
#define BF_LO(u) __uint_as_float((u) << 16)
#define BF_HI(u) __uint_as_float((u) & 0xffff0000u)

// =======================================================================
//                FAST PATH: bf16 weights + tagged-dataflow sync
// =======================================================================

// f32 -> bf16 conversion, 8 elems/thread. NT loads for the single-use f32 stream.
__global__ void __launch_bounds__(256) conv_bf16(const float* __restrict__ src,
                                                 unsigned* __restrict__ dst) {
  size_t i = ((size_t)blockIdx.x * blockDim.x + threadIdx.x) * 8;
  const nf4* s4 = (const nf4*)(src + i);
  nf4 a = __builtin_nontemporal_load(s4);
  nf4 b = __builtin_nontemporal_load(s4 + 1);
  uint4 o;
  o.x = (f2bf(a.y) << 16) | f2bf(a.x);
  o.y = (f2bf(a.w) << 16) | f2bf(a.z);
  o.z = (f2bf(b.y) << 16) | f2bf(b.x);
  o.w = (f2bf(b.w) << 16) | f2bf(b.z);
  *(uint4*)(dst + i / 2) = o;
}

// stage for layer 0: x is a plain dense row (g_emb or w_emb[act]); hin tagged.
__device__ void stage_l0(const float* __restrict__ x, const u64* __restrict__ th_hin,
                         unsigned tag, float* s_x, float* s_h) {
  const int tid = threadIdx.x;
  __syncthreads();                 // protect previous phase's LDS readers
  *(float4*)(s_x + tid * 4) = *(const float4*)(x + tid * 4);
#pragma unroll
  for (int r = 0; r < 4; ++r) {
    int e = tid + r * 512;
    s_h[e] = poll_tag(th_hin + e, tag);
  }
  __syncthreads();
}

// stage for layer 1: both x (= new h0) and hin (= old h1) are tagged.
__device__ void stage_l1(const u64* __restrict__ th_x, unsigned tagx,
                         const u64* __restrict__ th_hin, unsigned tagh,
                         float* s_x, float* s_h) {
  const int tid = threadIdx.x;
  __syncthreads();
#pragma unroll
  for (int r = 0; r < 4; ++r) {
    int e = tid + r * 512;
    s_x[e] = poll_tag(th_x + e, tagx);
    s_h[e] = poll_tag(th_hin + e, tagh);
  }
  __syncthreads();
}

// R13 compute core: wave = unit, full 2048-dot over both matrices.
// Dense float4 x/h from LDS (conflict-free), uint2 bf16 weights.
// Producer publishes tagged h via one atomic 8B agent store.
__device__ void layer_core(const unsigned* __restrict__ wiL, const unsigned* __restrict__ whL,
                           const float* __restrict__ bihL, const float* __restrict__ bhhL,
                           const float* s_x, const float* s_h,
                           u64* __restrict__ th_out, unsigned otag,
                           float* __restrict__ c, int j, int lane) {
  float4 xv[8], hv[8];
#pragma unroll
  for (int k = 0; k < 8; ++k) {
    int e = k * 256 + lane * 4;
    xv[k] = *(const float4*)(s_x + e);
    hv[k] = *(const float4*)(s_h + e);
  }

  float acc[4];
#pragma unroll
  for (int g = 0; g < 4; ++g) {
    const unsigned* wi = wiL + ((size_t)(g * HD + j) * HD >> 1);  // uint = 2 bf16
    const unsigned* wh = whL + ((size_t)(g * HD + j) * HD >> 1);
    float si = 0.0f, sh2 = 0.0f;
#pragma unroll
    for (int k = 0; k < 8; ++k) {
      int e2 = k * 128 + lane * 2;
      uint2 qa = *(const uint2*)(wi + e2);
      uint2 qb = *(const uint2*)(wh + e2);
      si  += BF_LO(qa.x) * xv[k].x + BF_HI(qa.x) * xv[k].y;
      si  += BF_LO(qa.y) * xv[k].z + BF_HI(qa.y) * xv[k].w;
      sh2 += BF_LO(qb.x) * hv[k].x + BF_HI(qb.x) * hv[k].y;
      sh2 += BF_LO(qb.y) * hv[k].z + BF_HI(qb.y) * hv[k].w;
    }
    acc[g] = si + sh2;
  }
#pragma unroll
  for (int off = 32; off > 0; off >>= 1) {
#pragma unroll
    for (int g = 0; g < 4; ++g) acc[g] += __shfl_xor(acc[g], off, 64);
  }
  if (lane == 0) {
    float gi = acc[0] + bihL[j]          + bhhL[j];
    float gf = acc[1] + bihL[HD + j]     + bhhL[HD + j];
    float gg = acc[2] + bihL[2 * HD + j] + bhhL[2 * HD + j];
    float go = acc[3] + bihL[3 * HD + j] + bhhL[3 * HD + j];
    float cn = sigmoidf(gf) * c[j] + sigmoidf(gi) * tanhf(gg);
    c[j] = cn;                                   // wg-private (same CU)
    float hval = sigmoidf(go) * tanhf(cn);
    st64_agent(&th_out[j], ((u64)otag << 32) | (u64)__float_as_uint(hval));
  }
}

// logits + categorical sample from LDS-staged h1 (redundant per wg, 8 waves)
__device__ int sample_from_lds(const float* s_h, const float* __restrict__ soft_w,
                               int t, float* lp_out, float* ent_out) {
  __shared__ float s_part[8][NACT];
  __shared__ float s_res[3];
  const int wave = threadIdx.x >> 6;
  const int lane = threadIdx.x & 63;

  float lg[NACT];
#pragma unroll
  for (int a = 0; a < NACT; ++a) lg[a] = 0.0f;
#pragma unroll
  for (int m = 0; m < 4; ++m) {
    int e = wave * 256 + m * 64 + lane;
    float hv = s_h[e];
    const float* sw = soft_w + (size_t)e * NACT;
    float4 r0 = *(const float4*)(sw);
    float4 r1 = *(const float4*)(sw + 4);
    float4 r2 = *(const float4*)(sw + 8);
    float4 r3 = *(const float4*)(sw + 12);
    lg[0]  += hv * r0.x; lg[1]  += hv * r0.y; lg[2]  += hv * r0.z; lg[3]  += hv * r0.w;
    lg[4]  += hv * r1.x; lg[5]  += hv * r1.y; lg[6]  += hv * r1.z; lg[7]  += hv * r1.w;
    lg[8]  += hv * r2.x; lg[9]  += hv * r2.y; lg[10] += hv * r2.z; lg[11] += hv * r2.w;
    lg[12] += hv * r3.x; lg[13] += hv * r3.y; lg[14] += hv * r3.z; lg[15] += hv * r3.w;
  }
#pragma unroll
  for (int off = 32; off > 0; off >>= 1) {
#pragma unroll
    for (int a = 0; a < NACT; ++a) lg[a] += __shfl_xor(lg[a], off, 64);
  }
  if (lane == 0) {
#pragma unroll
    for (int a = 0; a < NACT; ++a) s_part[wave][a] = lg[a];
  }
  __syncthreads();

  if (wave == 0 && lane < NACT) {
    float logit = 0.0f;
#pragma unroll
    for (int w = 0; w < 8; ++w) logit += s_part[w][lane];

    unsigned kt0, kt1, b0, b1;
    threefry(0u, 42u, 0u, (unsigned)t, kt0, kt1);
    threefry(kt0, kt1, 0u, (unsigned)lane, b0, b1);
    unsigned bits = b0 ^ b1;

    const float tiny = 1.17549435e-38f;
    float u = __uint_as_float((bits >> 9) | 0x3f800000u) - 1.0f;  // [0,1)
    u = fmaxf(tiny, u + tiny);
    float gmb = -logf(-logf(u));
    float z = logit + gmb;

    int idx = lane; float zz = z;
#pragma unroll
    for (int off = 8; off > 0; off >>= 1) {
      float oz = __shfl_xor(zz, off, NACT);
      int   oi = __shfl_xor(idx, off, NACT);
      if (oz > zz || (oz == zz && oi < idx)) { zz = oz; idx = oi; }
    }
    float mx = logit;
#pragma unroll
    for (int off = 8; off > 0; off >>= 1) mx = fmaxf(mx, __shfl_xor(mx, off, NACT));
    float sh = logit - mx;
    float se = expf(sh);
#pragma unroll
    for (int off = 8; off > 0; off >>= 1) se += __shfl_xor(se, off, NACT);
    float lp = sh - logf(se);
    float term = expf(lp) * lp;
#pragma unroll
    for (int off = 8; off > 0; off >>= 1) term += __shfl_xor(term, off, NACT);
    float lp_sel = __shfl(lp, idx, NACT);
    if (lane == 0) { s_res[0] = (float)idx; s_res[1] = lp_sel; s_res[2] = -term; }
  }
  __syncthreads();
  int act = (int)s_res[0];
  *lp_out = s_res[1];
  *ent_out = s_res[2];
  return act;
}

__global__ void __launch_bounds__(NTHR) ctrl2_kernel(
    const float* __restrict__ g_emb, const float* __restrict__ w_emb,
    const float* __restrict__ soft_w,
    const unsigned* __restrict__ wb_ih, const unsigned* __restrict__ wb_hh,
    const float* __restrict__ b_ih, const float* __restrict__ b_hh,
    float* __restrict__ out, u64* __restrict__ th0, u64* __restrict__ th1,
    float* __restrict__ cst) {
  __shared__ float s_x[HD];
  __shared__ float s_h[HD];
  float* c0 = cst;
  float* c1 = cst + HD;

  const int tid  = threadIdx.x;
  const int wave = tid >> 6;
  const int lane = tid & 63;
  const int j = (int)blockIdx.x * 8 + wave;   // hidden unit owned by this wave

  if (tid < 8) {
    int jj = (int)blockIdx.x * 8 + tid;
    c0[jj] = 0.0f; c1[jj] = 0.0f;             // wg-private; fenced by stage syncthreads
  }

  const unsigned* wi0 = wb_ih;             const unsigned* wh0 = wb_hh;
  const unsigned* wi1 = wb_ih + WL / 2;    const unsigned* wh1 = wb_hh + WL / 2;

  const float* x = g_emb;
  for (int t = 0; t < NSTEP; ++t) {
    int s = t & 1, ps = s ^ 1;
    // ---- layer 0: hin = h0^{(t-1)} (tag t, slot ps; t=0 -> init zeros tag 0) ----
    stage_l0(x, th0 + ps * HD, (unsigned)t, s_x, s_h);
    layer_core(wi0, wh0, b_ih, b_hh, s_x, s_h,
               th0 + s * HD, (unsigned)(t + 1), c0, j, lane);
    // ---- layer 1: x = h0^{(t)} (tag t+1), hin = h1^{(t-1)} (tag t) ----
    stage_l1(th0 + s * HD, (unsigned)(t + 1), th1 + ps * HD, (unsigned)t, s_x, s_h);
    layer_core(wi1, wh1, b_ih + 4 * HD, b_hh + 4 * HD, s_x, s_h,
               th1 + s * HD, (unsigned)(t + 1), c1, j, lane);
    // ---- sample from h1^{(t)} (tag t+1), staged into LDS ----
    __syncthreads();
#pragma unroll
    for (int r = 0; r < 4; ++r) {
      int e = tid + r * 512;
      s_h[e] = poll_tag(th1 + s * HD + e, (unsigned)(t + 1));
    }
    __syncthreads();
    float lp, en;
    int act = sample_from_lds(s_h, soft_w, t, &lp, &en);
    if (blockIdx.x == 0 && tid == 0) {
      out[t] = (float)act;
      out[NSTEP + t] = lp;
      out[2 * NSTEP + t] = en;
    }
    x = w_emb + (size_t)act * HD;
  }
}

// zero the tagged state (2 arrays x 2 slots x HD u64 = 8192 words)
__global__ void __launch_bounds__(1024) init_tags(u64* th) {
  th[(size_t)blockIdx.x * 1024 + threadIdx.x] = 0ull;
}

// =======================================================================
//          FALLBACK PATH: f32 weights direct (round-5-proven, 256x512)
// =======================================================================

__device__ void grid_bar_ctr(unsigned long long* ctr, unsigned long long target) {
  __syncthreads();
  if (threadIdx.x == 0) {
    __builtin_amdgcn_fence(__ATOMIC_SEQ_CST, "agent");
    __hip_atomic_fetch_add(ctr, 1ull, __ATOMIC_RELAXED, __HIP_MEMORY_SCOPE_AGENT);
    long guard = 0;
    while (__hip_atomic_load(ctr, __ATOMIC_RELAXED, __HIP_MEMORY_SCOPE_AGENT) < target &&
           guard < 20000000L) {
      __builtin_amdgcn_s_sleep(2);
      ++guard;
    }
    __builtin_amdgcn_fence(__ATOMIC_SEQ_CST, "agent");
  }
  __syncthreads();
}

__device__ int sample_step8(const float* __restrict__ h1g, const float* __restrict__ soft_w,
                            int t, float* lp_out, float* ent_out) {
  __shared__ float s_part[8][NACT];
  __shared__ float s_res[3];
  const int wave = threadIdx.x >> 6;
  const int lane = threadIdx.x & 63;

  float lg[NACT];
#pragma unroll
  for (int a = 0; a < NACT; ++a) lg[a] = 0.0f;
#pragma unroll
  for (int m = 0; m < 4; ++m) {
    int e = wave * 256 + m * 64 + lane;
    float hv = h1g[e];
    const float* sw = soft_w + (size_t)e * NACT;
    float4 r0 = *(const float4*)(sw);
    float4 r1 = *(const float4*)(sw + 4);
    float4 r2 = *(const float4*)(sw + 8);
    float4 r3 = *(const float4*)(sw + 12);
    lg[0]  += hv * r0.x; lg[1]  += hv * r0.y; lg[2]  += hv * r0.z; lg[3]  += hv * r0.w;
    lg[4]  += hv * r1.x; lg[5]  += hv * r1.y; lg[6]  += hv * r1.z; lg[7]  += hv * r1.w;
    lg[8]  += hv * r2.x; lg[9]  += hv * r2.y; lg[10] += hv * r2.z; lg[11] += hv * r2.w;
    lg[12] += hv * r3.x; lg[13] += hv * r3.y; lg[14] += hv * r3.z; lg[15] += hv * r3.w;
  }
#pragma unroll
  for (int off = 32; off > 0; off >>= 1) {
#pragma unroll
    for (int a = 0; a < NACT; ++a) lg[a] += __shfl_xor(lg[a], off, 64);
  }
  if (lane == 0) {
#pragma unroll
    for (int a = 0; a < NACT; ++a) s_part[wave][a] = lg[a];
  }
  __syncthreads();

  if (wave == 0 && lane < NACT) {
    float logit = 0.0f;
#pragma unroll
    for (int w = 0; w < 8; ++w) logit += s_part[w][lane];
    unsigned kt0, kt1, b0, b1;
    threefry(0u, 42u, 0u, (unsigned)t, kt0, kt1);
    threefry(kt0, kt1, 0u, (unsigned)lane, b0, b1);
    unsigned bits = b0 ^ b1;
    const float tiny = 1.17549435e-38f;
    float u = __uint_as_float((bits >> 9) | 0x3f800000u) - 1.0f;
    u = fmaxf(tiny, u + tiny);
    float gmb = -logf(-logf(u));
    float z = logit + gmb;
    int idx = lane; float zz = z;
#pragma unroll
    for (int off = 8; off > 0; off >>= 1) {
      float oz = __shfl_xor(zz, off, NACT);
      int   oi = __shfl_xor(idx, off, NACT);
      if (oz > zz || (oz == zz && oi < idx)) { zz = oz; idx = oi; }
    }
    float mx = logit;
#pragma unroll
    for (int off = 8; off > 0; off >>= 1) mx = fmaxf(mx, __shfl_xor(mx, off, NACT));
    float sh = logit - mx;
    float se = expf(sh);
#pragma unroll
    for (int off = 8; off > 0; off >>= 1) se += __shfl_xor(se, off, NACT);
    float lp = sh - logf(se);
    float term = expf(lp) * lp;
#pragma unroll
    for (int off = 8; off > 0; off >>= 1) term += __shfl_xor(term, off, NACT);
    float lp_sel = __shfl(lp, idx, NACT);
    if (lane == 0) { s_res[0] = (float)idx; s_res[1] = lp_sel; s_res[2] = -term; }
  }
  __syncthreads();
  int act = (int)s_res[0];
  *lp_out = s_res[1];
  *ent_out = s_res[2];
  return act;
}

__device__ void lstm_layer(const float* __restrict__ Wih, const float* __restrict__ Whh,
                           const float* __restrict__ bih, const float* __restrict__ bhh,
                           const float* __restrict__ x, const float* __restrict__ hin,
                           float* __restrict__ hout, float* __restrict__ c) {
  const int wave = threadIdx.x >> 6;
  const int lane = threadIdx.x & 63;
  const int j = (int)blockIdx.x * 8 + wave;

  float4 xv[8], hv[8];
#pragma unroll
  for (int k = 0; k < 8; ++k) {
    int e = k * 256 + lane * 4;
    xv[k] = *(const float4*)(x + e);
    hv[k] = *(const float4*)(hin + e);
  }
  float acc[4];
#pragma unroll
  for (int g = 0; g < 4; ++g) {
    const float* wi = Wih + (size_t)(g * HD + j) * HD;
    const float* wh = Whh + (size_t)(g * HD + j) * HD;
    float s = 0.0f;
#pragma unroll
    for (int k = 0; k < 8; ++k) {
      int e = k * 256 + lane * 4;
      float4 a4 = *(const float4*)(wi + e);
      float4 b4 = *(const float4*)(wh + e);
      s += a4.x * xv[k].x; s += a4.y * xv[k].y; s += a4.z * xv[k].z; s += a4.w * xv[k].w;
      s += b4.x * hv[k].x; s += b4.y * hv[k].y; s += b4.z * hv[k].z; s += b4.w * hv[k].w;
    }
    acc[g] = s;
  }
#pragma unroll
  for (int off = 32; off > 0; off >>= 1) {
#pragma unroll
    for (int g = 0; g < 4; ++g) acc[g] += __shfl_xor(acc[g], off, 64);
  }
  if (lane == 0) {
    float gi = acc[0] + bih[j]          + bhh[j];
    float gf = acc[1] + bih[HD + j]     + bhh[HD + j];
    float gg = acc[2] + bih[2 * HD + j] + bhh[2 * HD + j];
    float go = acc[3] + bih[3 * HD + j] + bhh[3 * HD + j];
    float cn = sigmoidf(gf) * c[j] + sigmoidf(gi) * tanhf(gg);
    c[j] = cn;
    hout[j] = sigmoidf(go) * tanhf(cn);
  }
}

__global__ void __launch_bounds__(NTHR_FB) ctrl_kernel(
    const float* __restrict__ g_emb, const float* __restrict__ w_emb,
    const float* __restrict__ soft_w, const float* __restrict__ w_ih,
    const float* __restrict__ w_hh, const float* __restrict__ b_ih,
    const float* __restrict__ b_hh, float* __restrict__ out, float* __restrict__ ws) {
  float* h0 = ws;
  float* h1 = ws + 2 * HD;
  float* c0 = ws + 4 * HD;
  float* c1 = ws + 5 * HD;
  unsigned long long* bar = (unsigned long long*)(ws + 6 * HD);

  if (threadIdx.x < 8) {
    int j = (int)blockIdx.x * 8 + (int)threadIdx.x;
    h0[j] = 0.0f; h1[j] = 0.0f; c0[j] = 0.0f; c1[j] = 0.0f;
  }
  unsigned long long ep = 1;
  grid_bar_ctr(bar, (ep++) * NWG_FB);

  const float* x = g_emb;
  for (int t = 0; t < NSTEP; ++t) {
    int q = t & 1;
    lstm_layer(w_ih, w_hh, b_ih, b_hh, x, h0 + q * HD, h0 + (1 - q) * HD, c0);
    grid_bar_ctr(bar, (ep++) * NWG_FB);
    lstm_layer(w_ih + WL, w_hh + WL, b_ih + 4 * HD, b_hh + 4 * HD,
               h0 + (1 - q) * HD, h1 + q * HD, h1 + (1 - q) * HD, c1);
    grid_bar_ctr(bar, (ep++) * NWG_FB);
    float lp, en;
    int act = sample_step8(h1 + (1 - q) * HD, soft_w, t, &lp, &en);
    if (blockIdx.x == 0 && threadIdx.x == 0) {
      out[t] = (float)act;
      out[NSTEP + t] = lp;
      out[2 * NSTEP + t] = en;
    }
    x = w_emb + (size_t)act * HD;
  }
}

__global__ void init_bar(unsigned long long* bar) { *bar = 0ull; }

extern "C" void kernel_launch(void* const* d_in, const int* in_sizes, int n_in,
                              void* d_out, int out_size, void* d_ws, size_t ws_size,
                              hipStream_t stream) {
  const float* g_emb  = (const float*)d_in[0];
  const float* w_emb  = (const float*)d_in[1];
  const float* soft_w = (const float*)d_in[2];
  const float* w_ih   = (const float*)d_in[3];
  const float* w_hh   = (const float*)d_in[4];
  const float* b_ih   = (const float*)d_in[5];
  const float* b_hh   = (const float*)d_in[6];

  const size_t wbytes = (size_t)NIH * 2 * sizeof(unsigned short);  // 134,217,728
  const size_t tagbytes = (size_t)8 * HD * sizeof(u64);            // th0[2]+th1[2] = 64KB (pad)
  const size_t need = wbytes + tagbytes + (size_t)2 * HD * sizeof(float) + 64;

  if (ws_size >= need) {
    unsigned* wb_ih = (unsigned*)d_ws;               // NIH bf16 = NIH/2 uints
    unsigned* wb_hh = wb_ih + NIH / 2;
    u64* th0 = (u64*)((char*)d_ws + wbytes);         // [2][HD] tagged
    u64* th1 = th0 + 2 * HD;                         // [2][HD] tagged
    float* cst = (float*)(th0 + 4 * HD);             // c0,c1 [2][HD]

    hipLaunchKernelGGL(init_tags, dim3(4 * HD * 2 / 1024), dim3(1024), 0, stream, th0);
    hipLaunchKernelGGL(conv_bf16, dim3(NIH / (256 * 8)), dim3(256), 0, stream, w_ih, wb_ih);
    hipLaunchKernelGGL(conv_bf16, dim3(NIH / (256 * 8)), dim3(256), 0, stream, w_hh, wb_hh);
    hipLaunchKernelGGL(ctrl2_kernel, dim3(NWG), dim3(NTHR), 0, stream,
                       g_emb, w_emb, soft_w, wb_ih, wb_hh, b_ih, b_hh,
                       (float*)d_out, th0, th1, cst);
  } else {
    float* ws = (float*)d_ws;
    unsigned long long* bar = (unsigned long long*)(ws + 6 * HD);
    hipLaunchKernelGGL(init_bar, dim3(1), dim3(1), 0, stream, bar);
    hipLaunchKernelGGL(ctrl_kernel, dim3(NWG_FB), dim3(NTHR_FB), 0, stream,
                       g_emb, w_emb, soft_w, w_ih, w_hh, b_ih, b_hh,
                       (float*)d_out, ws);
  }
}